// Round 5
// baseline (1152.617 us; speedup 1.0000x reference)
//
#include <hip/hip_runtime.h>
#include <cstdint>

#define NPTS 8192
#define NB 8
#define DS 512
#define CF 64
#define KNN 32
#define NFPS 8                        // FPS blocks; each runs TWO instances
#define NWORK 248
#define NCOSI 64
#define NITEMS (NCOSI + 2 * NB * DS)  // 64 cos chunks + 8192 knn+group items
#define DYNLDS 98304                  // occupancy limiter: 1 block/CU (spin protocol)

typedef float v2f __attribute__((ext_vector_type(2)));
typedef unsigned long long ull;

// ---- DPP wave-64 reductions (VALU only) -----------------------------------
// Dual interleaved max chains: two independent dependency chains pipelined
// step-by-step so each DPP hazard hides under the sibling chain's op.
__device__ __forceinline__ void wave_max63_dual(float& a, float& b) {
  int va, vb;
#define DSTEP(ctrl)                                                            \
  va = __builtin_amdgcn_update_dpp(0, __float_as_int(a), ctrl, 0xf, 0xf, true);\
  vb = __builtin_amdgcn_update_dpp(0, __float_as_int(b), ctrl, 0xf, 0xf, true);\
  a = fmaxf(a, __int_as_float(va)); b = fmaxf(b, __int_as_float(vb));
  DSTEP(0x111) DSTEP(0x112) DSTEP(0x114) DSTEP(0x118) DSTEP(0x142) DSTEP(0x143)
#undef DSTEP
}

__device__ __forceinline__ float wave_sum_bcast(float x) {
  int v;
  v = __builtin_amdgcn_update_dpp(0, __float_as_int(x), 0x111, 0xf, 0xf, true); x += __int_as_float(v);
  v = __builtin_amdgcn_update_dpp(0, __float_as_int(x), 0x112, 0xf, 0xf, true); x += __int_as_float(v);
  v = __builtin_amdgcn_update_dpp(0, __float_as_int(x), 0x114, 0xf, 0xf, true); x += __int_as_float(v);
  v = __builtin_amdgcn_update_dpp(0, __float_as_int(x), 0x118, 0xf, 0xf, true); x += __int_as_float(v);
  v = __builtin_amdgcn_update_dpp(0, __float_as_int(x), 0x142, 0xf, 0xf, true); x += __int_as_float(v);
  v = __builtin_amdgcn_update_dpp(0, __float_as_int(x), 0x143, 0xf, 0xf, true); x += __int_as_float(v);
  return __int_as_float(__builtin_amdgcn_readlane(__float_as_int(x), 63));
}

// zero acc[0..8] + done([13]); idxbuf stays 0xAA-poisoned (>=8192 sentinel).
__global__ __launch_bounds__(64) void zero_kernel(float* __restrict__ acc) {
  if (threadIdx.x < 16) acc[threadIdx.x] = 0.0f;
}

// ONE fused kernel, 256 blocks x 512 thr, dynamic LDS 98.3KB => 1 block/CU =>
// all 256 blocks co-resident => producer/consumer spin deadlock-free.
//   blocks 0..7   : FPS — R14: DUAL-INSTANCE blocks. Evidence (R1 win was
//                   latency cuts; R2 regression was exposed latency; R3/R4
//                   micro-cuts null): per-iter cost is serial chain latency,
//                   ~2x any instruction accounting. Fix by ILP: each block
//                   runs TWO independent FPS instances; A's DPP chains /
//                   barrier tree / coord fetch latency hides under B's work
//                   and vice versa. One shared barrier per iteration. Winner
//                   coords now fetched from GLOBAL (L2-hot, uniform addr) —
//                   LDS coord table deleted (can't fit two).
//   blocks 8..255 : workers with STATIC staggered assignment (R8 lesson).
__global__ __launch_bounds__(512, 2) void fused_kernel(
    const float* __restrict__ logits, const float* __restrict__ logits1,
    const float* __restrict__ p0first, const float* __restrict__ p0sec,
    int* __restrict__ idxbuf, float* __restrict__ acc,
    int* __restrict__ done, float* __restrict__ out) {
  extern __shared__ char smem[];
  __shared__ __align__(16) ull wslotA[2][8];
  __shared__ __align__(16) ull wslotB[2][8];
  __shared__ int wtot[8];
  __shared__ int s_bl[2];
  __shared__ int ctr, eqctr, s_center;
  __shared__ float wloss[8];

  const int blk = blockIdx.x;
  const int t = threadIdx.x;

  if (blk < NFPS) {
    // ========= FPS: two instances per block, 1 barrier/iter ================
    const int iA = blk * 2, iB = blk * 2 + 1;
    const float* pA = ((iA >> 3) ? p0sec : p0first) + (size_t)(iA & 7) * NPTS * 3;
    const float* pB = ((iB >> 3) ? p0sec : p0first) + (size_t)(iB & 7) * NPTS * 3;
    int* idxA = idxbuf + iA * DS;
    int* idxB = idxbuf + iB * DS;
    const int lane = t & 63, wave = t >> 6;

    // lane-contiguous mapping: thread t owns points e = t*16 + j (j=0..15);
    // v2f group g holds j = 2g (.x) and j = 2g+1 (.y).
    v2f pxA[8], pyA[8], pzA[8], dA[8];
    v2f pxB[8], pyB[8], pzB[8], dB[8];
    {
      const float4* a4 = (const float4*)pA;
      const float4* b4 = (const float4*)pB;
#pragma unroll
      for (int k = 0; k < 4; ++k) {
        float4 v0 = a4[t * 12 + 3 * k + 0];
        float4 v1 = a4[t * 12 + 3 * k + 1];
        float4 v2 = a4[t * 12 + 3 * k + 2];
        pxA[2 * k]     = (v2f){v0.x, v0.w};
        pyA[2 * k]     = (v2f){v0.y, v1.x};
        pzA[2 * k]     = (v2f){v0.z, v1.y};
        pxA[2 * k + 1] = (v2f){v1.z, v2.y};
        pyA[2 * k + 1] = (v2f){v1.w, v2.z};
        pzA[2 * k + 1] = (v2f){v2.x, v2.w};
        dA[2 * k] = (v2f){3.4e38f, 3.4e38f};
        dA[2 * k + 1] = (v2f){3.4e38f, 3.4e38f};
        float4 u0 = b4[t * 12 + 3 * k + 0];
        float4 u1 = b4[t * 12 + 3 * k + 1];
        float4 u2 = b4[t * 12 + 3 * k + 2];
        pxB[2 * k]     = (v2f){u0.x, u0.w};
        pyB[2 * k]     = (v2f){u0.y, u1.x};
        pzB[2 * k]     = (v2f){u0.z, u1.y};
        pxB[2 * k + 1] = (v2f){u1.z, u2.y};
        pyB[2 * k + 1] = (v2f){u1.w, u2.z};
        pzB[2 * k + 1] = (v2f){u2.x, u2.w};
        dB[2 * k] = (v2f){3.4e38f, 3.4e38f};
        dB[2 * k + 1] = (v2f){3.4e38f, 3.4e38f};
      }
    }
#pragma unroll
    for (int g = 0; g < 8; ++g) {
      asm("" : "+v"(pxA[g]), "+v"(pyA[g]), "+v"(pzA[g]));  // no remat (R4)
      asm("" : "+v"(pxB[g]), "+v"(pyB[g]), "+v"(pzB[g]));
    }
    if (t == 0) {
      __hip_atomic_store(&idxA[0], 0, __ATOMIC_RELAXED, __HIP_MEMORY_SCOPE_AGENT);
      __hip_atomic_store(&idxB[0], 0, __ATOMIC_RELAXED, __HIP_MEMORY_SCOPE_AGENT);
    }
    float wxA = pA[0], wyA = pA[1], wzA = pA[2];  // seeds = point 0
    float wxB = pB[0], wyB = pB[1], wzB = pB[2];

    for (int it = 0; it < DS - 1; ++it) {
      v2f ax = (v2f){wxA, wxA}, ay = (v2f){wyA, wyA}, az = (v2f){wzA, wzA};
      v2f bx = (v2f){wxB, wxB}, by = (v2f){wyB, wyB}, bz = (v2f){wzB, wzB};
#pragma unroll
      for (int g = 0; g < 8; ++g) {
        v2f dxa = pxA[g] - ax, dya = pyA[g] - ay, dza = pzA[g] - az;
        v2f nda = dxa * dxa + dya * dya + dza * dza;
        dA[g] = __builtin_elementwise_min(dA[g], nda);
        v2f dxb = pxB[g] - bx, dyb = pyB[g] - by, dzb = pzB[g] - bz;
        v2f ndb = dxb * dxb + dyb * dyb + dzb * dzb;
        dB[g] = __builtin_elementwise_min(dB[g], ndb);
      }
      // lane max, balanced trees (fmax exactly assoc/commut -> bit-identical)
      v2f a0 = __builtin_elementwise_max(dA[0], dA[1]);
      v2f a1 = __builtin_elementwise_max(dA[2], dA[3]);
      v2f a2 = __builtin_elementwise_max(dA[4], dA[5]);
      v2f a3 = __builtin_elementwise_max(dA[6], dA[7]);
      v2f b0 = __builtin_elementwise_max(dB[0], dB[1]);
      v2f b1 = __builtin_elementwise_max(dB[2], dB[3]);
      v2f b2 = __builtin_elementwise_max(dB[4], dB[5]);
      v2f b3 = __builtin_elementwise_max(dB[6], dB[7]);
      v2f a4 = __builtin_elementwise_max(a0, a1);
      v2f a5 = __builtin_elementwise_max(a2, a3);
      v2f b4 = __builtin_elementwise_max(b0, b1);
      v2f b5 = __builtin_elementwise_max(b2, b3);
      v2f a6 = __builtin_elementwise_max(a4, a5);
      v2f b6 = __builtin_elementwise_max(b4, b5);
      float lmA = fmaxf(a6.x, a6.y);
      float lmB = fmaxf(b6.x, b6.y);
      // wave max, dual interleaved chains
      float rA = lmA, rB = lmB;
      wave_max63_dual(rA, rB);
      float wmA = __int_as_float(__builtin_amdgcn_readlane(__float_as_int(rA), 63));
      float wmB = __int_as_float(__builtin_amdgcn_readlane(__float_as_int(rB), 63));
      // wave tie-break: lowest candidate lane == smallest e (contiguous map)
      ull cmA = __ballot(lmA == wmA);
      ull cmB = __ballot(lmB == wmB);
      int wlA = (int)__ffsll(cmA) - 1;
      int wlB = (int)__ffsll(cmB) - 1;
      if (lane == wlA) {
        int jb = 0;
#pragma unroll
        for (int jp = 15; jp >= 0; --jp) {
          float dv = (jp & 1) ? dA[jp >> 1].y : dA[jp >> 1].x;
          if (dv == lmA) jb = jp;  // min j achieving lm
        }
        unsigned e_best = ((unsigned)t << 4) | (unsigned)jb;
        wslotA[it & 1][wave] =
            (((ull)__float_as_uint(wmA)) << 32) | (ull)(8191u - e_best);
      }
      if (lane == wlB) {
        int jb = 0;
#pragma unroll
        for (int jp = 15; jp >= 0; --jp) {
          float dv = (jp & 1) ? dB[jp >> 1].y : dB[jp >> 1].x;
          if (dv == lmB) jb = jp;
        }
        unsigned e_best = ((unsigned)t << 4) | (unsigned)jb;
        wslotB[it & 1][wave] =
            (((ull)__float_as_uint(wmB)) << 32) | (ull)(8191u - e_best);
      }
      // raw barrier: drain LDS only; publish stores stay in flight (R13)
      asm volatile("s_waitcnt lgkmcnt(0)\n\ts_barrier" ::: "memory");
      {
        const ull* wsA = wslotA[it & 1];
        const ull* wsB = wslotB[it & 1];
        ull kA0 = wsA[0], kA1 = wsA[1], kA2 = wsA[2], kA3 = wsA[3];
        ull kA4 = wsA[4], kA5 = wsA[5], kA6 = wsA[6], kA7 = wsA[7];
        ull kB0 = wsB[0], kB1 = wsB[1], kB2 = wsB[2], kB3 = wsB[3];
        ull kB4 = wsB[4], kB5 = wsB[5], kB6 = wsB[6], kB7 = wsB[7];
        ull qa0 = kA0 > kA1 ? kA0 : kA1, qa1 = kA2 > kA3 ? kA2 : kA3;
        ull qa2 = kA4 > kA5 ? kA4 : kA5, qa3 = kA6 > kA7 ? kA6 : kA7;
        ull qb0 = kB0 > kB1 ? kB0 : kB1, qb1 = kB2 > kB3 ? kB2 : kB3;
        ull qb2 = kB4 > kB5 ? kB4 : kB5, qb3 = kB6 > kB7 ? kB6 : kB7;
        ull ra0 = qa0 > qa1 ? qa0 : qa1, ra1 = qa2 > qa3 ? qa2 : qa3;
        ull rb0 = qb0 > qb1 ? qb0 : qb1, rb1 = qb2 > qb3 ? qb2 : qb3;
        ull kfA = ra0 > ra1 ? ra0 : ra1;
        ull kfB = rb0 > rb1 ? rb0 : rb1;
        unsigned eA = 8191u - (unsigned)(kfA & 0xffffffffu);
        unsigned eB = 8191u - (unsigned)(kfB & 0xffffffffu);
        if (t == 0) {
          __hip_atomic_store(&idxA[it + 1], (int)eA, __ATOMIC_RELAXED,
                             __HIP_MEMORY_SCOPE_AGENT);
          __hip_atomic_store(&idxB[it + 1], (int)eB, __ATOMIC_RELAXED,
                             __HIP_MEMORY_SCOPE_AGENT);
        }
        // winner coords from global (L2-hot, uniform addr); the two fetches
        // and the next iteration's sibling work overlap.
        const float* cA = pA + (size_t)eA * 3;
        const float* cB = pB + (size_t)eB * 3;
        float nAx = cA[0], nAy = cA[1], nAz = cA[2];
        float nBx = cB[0], nBy = cB[1], nBz = cB[2];
        wxA = nAx; wyA = nAy; wzA = nAz;
        wxB = nBx; wyB = nBy; wzB = nBz;
      }
    }
  } else {
    // ================= worker: static staggered items ======================
    int* hb0 = (int*)smem;                         // [2][2048] = 16 KB
    int* hb1 = (int*)(smem + 16384);               // [2][2048] = 16 KB
    float* Drows = (float*)(smem + 32768);         // [33][64] = 8448 B
    int* nbr = (int*)(smem + 41216);               // [32]
    int* eq = (int*)(smem + 41344);                // [256]
    const int lane = t & 63, wave = t >> 6;
    const int w0 = blk - NFPS;  // 0..247
    for (int item = w0; item < NITEMS; item += NWORK) {
      if (item < NCOSI) {
        // ---- cos chunk: rows item*1024 .. +1023, 2 rows/thread ------------
        float cv = 0.0f;
#pragma unroll
        for (int rr = 0; rr < 2; ++rr) {
          int row = item * 1024 + rr * 512 + t;
          const float4* A = (const float4*)(logits + (size_t)row * CF);
          const float4* Bv = (const float4*)(logits1 + (size_t)row * CF);
          float ab = 0.f, aa = 0.f, bb = 0.f;
#pragma unroll
          for (int i = 0; i < 16; ++i) {
            float4 a = A[i], c4 = Bv[i];
            ab += a.x * c4.x + a.y * c4.y + a.z * c4.z + a.w * c4.w;
            aa += a.x * a.x + a.y * a.y + a.z * a.z + a.w * a.w;
            bb += c4.x * c4.x + c4.y * c4.y + c4.z * c4.z + c4.w * c4.w;
          }
          cv += ab / fmaxf(sqrtf(aa) * sqrtf(bb), 1e-8f);
        }
        cv = wave_sum_bcast(cv);
        if (lane == 0) wloss[wave] = cv;
        __syncthreads();
        if (t == 0) {
          float s = 0.f;
#pragma unroll
          for (int w = 0; w < 8; ++w) s += wloss[w];
          atomicAdd(&acc[0], s);
        }
        __syncthreads();
      } else {
        // ---- knn+group for one query --------------------------------------
        const int qi2 = item - NCOSI;
        const int m = qi2 >> 4, pair = qi2 & 15;
        const int g = pair * DS + m;
        const int view = pair >> 3, b = pair & 7;
        const float* p = (view ? p0sec : p0first) + (size_t)b * NPTS * 3;
        // vectorized point load: 16 consecutive points = 12 dwordx4 / thread
        float f48[48];
        {
          const float4* p4 = (const float4*)p;
#pragma unroll
          for (int i = 0; i < 12; ++i) {
            float4 v4 = p4[t * 12 + i];
            f48[i * 4 + 0] = v4.x; f48[i * 4 + 1] = v4.y;
            f48[i * 4 + 2] = v4.z; f48[i * 4 + 3] = v4.w;
          }
        }
        for (int k = t; k < 4096; k += 512) hb0[k] = 0;
        if (t == 0) {
          int ce;
          while ((unsigned)(ce = __hip_atomic_load(&idxbuf[g], __ATOMIC_RELAXED,
                                                   __HIP_MEMORY_SCOPE_AGENT)) >= 8192u)
            __builtin_amdgcn_s_sleep(2);
          s_center = ce;
        }
        __syncthreads();
        const int ci = s_center;
        const float qx = p[ci * 3], qy = p[ci * 3 + 1], qz = p[ci * 3 + 2];
        const float qq = qx * qx + qy * qy + qz * qz;
        const int cpy = (t & 1) << 11;  // histogram copy (2 copies)
        unsigned sk[16];  // keys for points e = t*16 + j
#pragma unroll
        for (int j = 0; j < 16; ++j) {
          float sx = f48[j * 3], sy = f48[j * 3 + 1], sz = f48[j * 3 + 2];
          float ss = sx * sx + sy * sy + sz * sz;
          float dt = qx * sx + qy * sy + qz * sz;
          float d = qq + ss - 2.0f * dt;  // same formula as reference
          unsigned u = __float_as_uint(d);
          u = (u & 0x80000000u) ? ~u : (u | 0x80000000u);  // sortable
          sk[j] = u;
        }
        int rrank = 31;
        // ---- pass A: top 11 bits, 2048 bins -------------------------------
#pragma unroll
        for (int j = 0; j < 16; ++j) atomicAdd(&hb0[cpy + (sk[j] >> 21)], 1);
        __syncthreads();
        unsigned pA, pAB, V;
        {
          int b0 = t << 2;
          int c0 = hb0[b0] + hb0[2048 + b0];
          int c1 = hb0[b0 + 1] + hb0[2048 + b0 + 1];
          int c2 = hb0[b0 + 2] + hb0[2048 + b0 + 2];
          int c3 = hb0[b0 + 3] + hb0[2048 + b0 + 3];
          int s = c0 + c1 + c2 + c3;
          int inc = s;
#pragma unroll
          for (int o = 1; o < 64; o <<= 1) {
            int v = __shfl_up(inc, o, 64);
            if (lane >= o) inc += v;
          }
          if (lane == 63) wtot[wave] = inc;
          for (int k = t; k < 4096; k += 512) hb1[k] = 0;  // zero B during scan
          __syncthreads();
          int off = 0;
#pragma unroll
          for (int w = 0; w < 8; ++w) off += (w < wave) ? wtot[w] : 0;
          int exc = off + inc - s;
          if (rrank >= exc && rrank < exc + s) {
            int r2 = rrank - exc; int bin, less;
            if (r2 < c0) { bin = 0; less = 0; }
            else if (r2 < c0 + c1) { bin = 1; less = c0; }
            else if (r2 < c0 + c1 + c2) { bin = 2; less = c0 + c1; }
            else { bin = 3; less = c0 + c1 + c2; }
            s_bl[0] = b0 + bin; s_bl[1] = exc + less;
          }
          __syncthreads();
          pA = (unsigned)s_bl[0];
          rrank -= s_bl[1];
        }
        // ---- pass B: bits [20:10], 2048 bins ------------------------------
#pragma unroll
        for (int j = 0; j < 16; ++j) {
          unsigned u = sk[j];
          if ((u >> 21) == pA) atomicAdd(&hb1[cpy + ((u >> 10) & 2047)], 1);
        }
        __syncthreads();
        {
          int b0 = t << 2;
          int c0 = hb1[b0] + hb1[2048 + b0];
          int c1 = hb1[b0 + 1] + hb1[2048 + b0 + 1];
          int c2 = hb1[b0 + 2] + hb1[2048 + b0 + 2];
          int c3 = hb1[b0 + 3] + hb1[2048 + b0 + 3];
          int s = c0 + c1 + c2 + c3;
          int inc = s;
#pragma unroll
          for (int o = 1; o < 64; o <<= 1) {
            int v = __shfl_up(inc, o, 64);
            if (lane >= o) inc += v;
          }
          if (lane == 63) wtot[wave] = inc;
          for (int k = t; k < 4096; k += 512) hb0[k] = 0;  // zero C buf
          __syncthreads();
          int off = 0;
#pragma unroll
          for (int w = 0; w < 8; ++w) off += (w < wave) ? wtot[w] : 0;
          int exc = off + inc - s;
          if (rrank >= exc && rrank < exc + s) {
            int r2 = rrank - exc; int bin, less;
            if (r2 < c0) { bin = 0; less = 0; }
            else if (r2 < c0 + c1) { bin = 1; less = c0; }
            else if (r2 < c0 + c1 + c2) { bin = 2; less = c0 + c1; }
            else { bin = 3; less = c0 + c1 + c2; }
            s_bl[0] = b0 + bin; s_bl[1] = exc + less;
          }
          __syncthreads();
          pAB = (pA << 11) | (unsigned)s_bl[0];
          rrank -= s_bl[1];
        }
        // ---- pass C: bits [9:0], 1024 bins --------------------------------
        const int cpyC = (t & 1) << 10;
#pragma unroll
        for (int j = 0; j < 16; ++j) {
          unsigned u = sk[j];
          if ((u >> 10) == pAB) atomicAdd(&hb0[cpyC + (u & 1023)], 1);
        }
        __syncthreads();
        {
          int b0 = t << 1;
          int c0 = hb0[b0] + hb0[1024 + b0];
          int c1 = hb0[b0 + 1] + hb0[1024 + b0 + 1];
          int s = c0 + c1;
          int inc = s;
#pragma unroll
          for (int o = 1; o < 64; o <<= 1) {
            int v = __shfl_up(inc, o, 64);
            if (lane >= o) inc += v;
          }
          if (lane == 63) wtot[wave] = inc;
          __syncthreads();
          int off = 0;
#pragma unroll
          for (int w = 0; w < 8; ++w) off += (w < wave) ? wtot[w] : 0;
          int exc = off + inc - s;
          if (rrank >= exc && rrank < exc + s) {
            int r2 = rrank - exc;
            if (r2 < c0) { s_bl[0] = b0; s_bl[1] = exc; }
            else { s_bl[0] = b0 + 1; s_bl[1] = exc + c0; }
          }
          if (t == 0) { ctr = 0; eqctr = 0; }  // folded init (was own barrier)
          __syncthreads();
          V = (pAB << 10) | (unsigned)s_bl[0];
          rrank -= s_bl[1];
        }
        // ---- output set: keys < V, plus (rrank+1) smallest-index == V -----
#pragma unroll
        for (int j = 0; j < 16; ++j) {
          unsigned u = sk[j];
          if (u < V) {
            int s = atomicAdd(&ctr, 1);
            nbr[s] = t * 16 + j;
          } else if (u == V) {
            int s2 = atomicAdd(&eqctr, 1);
            if (s2 < 256) eq[s2] = t * 16 + j;
          }
        }
        __syncthreads();
        if (t == 0) {
          int need = rrank + 1;
          int E = eqctr; if (E > 256) E = 256;
          int base = KNN - need;
          for (int s = 0; s < need; ++s) {
            int mi = 0;
            for (int i = 1; i < E; ++i)
              if (eq[i] < eq[mi]) mi = i;
            nbr[base + s] = eq[mi];
            eq[mi] = 0x7fffffff;
          }
        }
        __syncthreads();
        // ---- group loss (rows 0..31 = neighbors, row 32 = center) ---------
        const float* f = (view ? logits1 : logits) + (size_t)b * NPTS * CF;
        for (int r = wave; r < 33; r += 8) {
          int e = (r < 32) ? nbr[r] : ci;
          Drows[r * 64 + lane] = f[(size_t)e * CF + lane];
        }
        __syncthreads();
        float avg = 0.0f;
#pragma unroll
        for (int r = 0; r < 33; ++r) avg += Drows[r * 64 + lane];
        avg *= (1.0f / 33.0f);
        float na = wave_sum_bcast(avg * avg);
        const float rsna = sqrtf(na);
        float loss = 0.0f;
        for (int r = wave; r < 33; r += 8) {
          float d = Drows[r * 64 + lane];
          float d0 = wave_sum_bcast(d * avg);
          float n0 = wave_sum_bcast(d * d);
          float den = fmaxf(sqrtf(n0) * rsna, 1e-8f);
          loss += -200.0f * (d0 / den) - 0.5f * log1pf(40.0f * n0);
        }
        if (lane == 0) wloss[wave] = loss;
        __syncthreads();
        if (t == 0) {
          float s = 0.f;
#pragma unroll
          for (int w = 0; w < 8; ++w) s += wloss[w];
          atomicAdd(&acc[1 + b], s * (1.0f / 33.0f));
        }
        __syncthreads();
      }
    }
    // ---- completion + last-block finalize --------------------------------
    __syncthreads();
    if (t == 0) {
      int d = __hip_atomic_fetch_add(done, 1, __ATOMIC_ACQ_REL, __HIP_MEMORY_SCOPE_AGENT);
      if (d == NWORK - 1) {
        float a0 = __hip_atomic_load(&acc[0], __ATOMIC_ACQUIRE, __HIP_MEMORY_SCOPE_AGENT);
        float gsum = 0.0f;
        for (int bb = 0; bb < 8; ++bb) {
          float Sb = __hip_atomic_load(&acc[1 + bb], __ATOMIC_ACQUIRE, __HIP_MEMORY_SCOPE_AGENT);
          gsum = (gsum + Sb) * (1.0f / 512.0f);  // /512 exact (pow2)
        }
        gsum *= 0.125f;  // / b
        out[0] = -a0 / 65536.0f + gsum + gsum;
      }
    }
  }
}

extern "C" void kernel_launch(void* const* d_in, const int* in_sizes, int n_in,
                              void* d_out, int out_size, void* d_ws, size_t ws_size,
                              hipStream_t stream) {
  (void)in_sizes; (void)n_in; (void)out_size; (void)ws_size;
  const float* logits  = (const float*)d_in[0];
  const float* logits1 = (const float*)d_in[1];
  const float* p0first = (const float*)d_in[2];
  const float* p0sec   = (const float*)d_in[3];
  float* out = (float*)d_out;

  float* acc = (float*)d_ws;           // [0]=cosSum, [1..8]=S[b], [13]=done
  int* done  = (int*)d_ws + 13;
  int* idxbuf = (int*)d_ws + 16;       // [2*8*512]; 0xAA poison = "unpublished"

  zero_kernel<<<1, 64, 0, stream>>>(acc);
  fused_kernel<<<NFPS + NWORK, 512, DYNLDS, stream>>>(logits, logits1, p0first, p0sec,
                                                      idxbuf, acc, done, out);
}

// Round 6
// 542.706 us; speedup vs baseline: 2.1238x; 2.1238x over previous
//
#include <hip/hip_runtime.h>
#include <cstdint>

#define NPTS 8192
#define NB 8
#define DS 512
#define CF 64
#define KNN 32
#define NFPS 16
#define NWORK 240
#define NCOSI 64
#define NITEMS (NCOSI + 2 * NB * DS)  // 64 cos chunks + 8192 knn+group items
#define DYNLDS 98304                  // max(fps ldsP 96KB, worker bufs ~42KB)
#define PROGSTRIDE 32                 // ints; one 128-B line per instance

typedef float v2f __attribute__((ext_vector_type(2)));
typedef unsigned long long ull;

// ---- DPP wave-64 reductions (VALU only) -----------------------------------
__device__ __forceinline__ float wave_max63(float x) {
  int v;
  v = __builtin_amdgcn_update_dpp(0, __float_as_int(x), 0x111, 0xf, 0xf, true); x = fmaxf(x, __int_as_float(v));
  v = __builtin_amdgcn_update_dpp(0, __float_as_int(x), 0x112, 0xf, 0xf, true); x = fmaxf(x, __int_as_float(v));
  v = __builtin_amdgcn_update_dpp(0, __float_as_int(x), 0x114, 0xf, 0xf, true); x = fmaxf(x, __int_as_float(v));
  v = __builtin_amdgcn_update_dpp(0, __float_as_int(x), 0x118, 0xf, 0xf, true); x = fmaxf(x, __int_as_float(v));
  v = __builtin_amdgcn_update_dpp(0, __float_as_int(x), 0x142, 0xf, 0xf, true); x = fmaxf(x, __int_as_float(v));
  v = __builtin_amdgcn_update_dpp(0, __float_as_int(x), 0x143, 0xf, 0xf, true); x = fmaxf(x, __int_as_float(v));
  return x;  // valid in lane 63
}

__device__ __forceinline__ float wave_sum_bcast(float x) {
  int v;
  v = __builtin_amdgcn_update_dpp(0, __float_as_int(x), 0x111, 0xf, 0xf, true); x += __int_as_float(v);
  v = __builtin_amdgcn_update_dpp(0, __float_as_int(x), 0x112, 0xf, 0xf, true); x += __int_as_float(v);
  v = __builtin_amdgcn_update_dpp(0, __float_as_int(x), 0x114, 0xf, 0xf, true); x += __int_as_float(v);
  v = __builtin_amdgcn_update_dpp(0, __float_as_int(x), 0x118, 0xf, 0xf, true); x += __int_as_float(v);
  v = __builtin_amdgcn_update_dpp(0, __float_as_int(x), 0x142, 0xf, 0xf, true); x += __int_as_float(v);
  v = __builtin_amdgcn_update_dpp(0, __float_as_int(x), 0x143, 0xf, 0xf, true); x += __int_as_float(v);
  return __int_as_float(__builtin_amdgcn_readlane(__float_as_int(x), 63));
}

// zero acc[0..8] + done([13]); idxbuf/prog stay 0xAA-poisoned (negative /
// >=8192 sentinels).
__global__ __launch_bounds__(64) void zero_kernel(float* __restrict__ acc) {
  if (threadIdx.x < 16) acc[threadIdx.x] = 0.0f;
}

// ONE fused kernel, 256 blocks x 512 thr, dynamic LDS 98.3KB => 1 block/CU =>
// all 256 blocks co-resident => producer/consumer spin deadlock-free.
//   blocks 0..15  : FPS — R15: R13 body + DECOUPLED PUBLICATION. Theory (R5's
//                   exact-2x regression with 2 publish stores/iter): per-iter
//                   cost is store-queue backpressure — the idx frontier line
//                   is polled by ~240 consumer blocks, each store re-acquires
//                   the contended line (~1-2k cy), the queue fills, wave 0
//                   stalls, the barrier spreads it. Fix: workers poll a
//                   per-instance PROG counter on its own 128-B line, RELEASE-
//                   published once per 8 iters; idx stores stay relaxed and
//                   are now write-mostly/read-once (uncontended).
//   blocks 16..255: workers with STATIC staggered assignment (R8 lesson).
__global__ __launch_bounds__(512, 2) void fused_kernel(
    const float* __restrict__ logits, const float* __restrict__ logits1,
    const float* __restrict__ p0first, const float* __restrict__ p0sec,
    int* __restrict__ idxbuf, int* __restrict__ progb, float* __restrict__ acc,
    int* __restrict__ done, float* __restrict__ out) {
  extern __shared__ char smem[];
  __shared__ __align__(16) ull wslot[2][8];
  __shared__ int wtot[8];
  __shared__ int s_bl[2];
  __shared__ int ctr, eqctr, s_center;
  __shared__ float wloss[8];

  const int blk = blockIdx.x;
  const int t = threadIdx.x;

  if (blk < NFPS) {
    // ================= FPS (8 waves, 1 raw barrier/iter) ===================
    float* ldsP = (float*)smem;  // 96 KB winner-lookup table (linear copy of p)
    const int view = blk >> 3, b = blk & 7;
    const float* p = (view ? p0sec : p0first) + (size_t)b * NPTS * 3;
    int* idx_out = idxbuf + blk * DS;
    int* prg = progb + blk * PROGSTRIDE;
    const int lane = t & 63, wave = t >> 6;
    // lane-contiguous mapping: thread t owns points e = t*16 + j, j = 0..15;
    // v2f group g holds j = 2g (.x) and j = 2g+1 (.y).
    v2f px2[8], py2[8], pz2[8], dist2[8];
    {
      float f48[48];
      const float4* p4 = (const float4*)p;
      float4* l4 = (float4*)ldsP;
#pragma unroll
      for (int i = 0; i < 12; ++i) {
        float4 v4 = p4[t * 12 + i];
        l4[t * 12 + i] = v4;  // ldsP[q] == p[q]
        f48[i * 4 + 0] = v4.x; f48[i * 4 + 1] = v4.y;
        f48[i * 4 + 2] = v4.z; f48[i * 4 + 3] = v4.w;
      }
#pragma unroll
      for (int g = 0; g < 8; ++g) {
        px2[g] = (v2f){f48[6 * g + 0], f48[6 * g + 3]};
        py2[g] = (v2f){f48[6 * g + 1], f48[6 * g + 4]};
        pz2[g] = (v2f){f48[6 * g + 2], f48[6 * g + 5]};
        dist2[g] = (v2f){3.4e38f, 3.4e38f};
      }
    }
#pragma unroll
    for (int g = 0; g < 8; ++g) {
      asm("" : "+v"(px2[g]), "+v"(py2[g]), "+v"(pz2[g]));  // no remat (R4)
    }
    if (t == 0) {
      __hip_atomic_store(&idx_out[0], 0, __ATOMIC_RELAXED, __HIP_MEMORY_SCOPE_AGENT);
      // release: idx[0] visible before prog=1
      __hip_atomic_store(&prg[0], 1, __ATOMIC_RELEASE, __HIP_MEMORY_SCOPE_AGENT);
    }
    float wx = p[0], wy = p[1], wz = p[2];  // seed = point 0
    __syncthreads();  // once; staging drain is fine here

    for (int it = 0; it < DS - 1; ++it) {
      v2f wx2 = (v2f){wx, wx}, wy2 = (v2f){wy, wy}, wz2 = (v2f){wz, wz};
#pragma unroll
      for (int g = 0; g < 8; ++g) {
        v2f dx = px2[g] - wx2, dy = py2[g] - wy2, dz = pz2[g] - wz2;
        v2f nd = dx * dx + dy * dy + dz * dz;
        dist2[g] = __builtin_elementwise_min(dist2[g], nd);
      }
      // lane max via balanced tree (fmax exactly assoc/commut -> identical)
      v2f m0 = __builtin_elementwise_max(dist2[0], dist2[1]);
      v2f m1 = __builtin_elementwise_max(dist2[2], dist2[3]);
      v2f m2 = __builtin_elementwise_max(dist2[4], dist2[5]);
      v2f m3 = __builtin_elementwise_max(dist2[6], dist2[7]);
      v2f n0 = __builtin_elementwise_max(m0, m1);
      v2f n1 = __builtin_elementwise_max(m2, m3);
      v2f q = __builtin_elementwise_max(n0, n1);
      float lm = fmaxf(q.x, q.y);
      // wave max + broadcast
      float wmv = wave_max63(lm);
      float wm = __int_as_float(__builtin_amdgcn_readlane(__float_as_int(wmv), 63));
      // wave tie-break: lowest candidate lane == smallest e (contiguous map)
      ull cmask = __ballot(lm == wm);
      int winlane = (int)__ffsll(cmask) - 1;
      if (lane == winlane) {
        int jbest = 0;
#pragma unroll
        for (int jp = 15; jp >= 0; --jp) {
          float dv = (jp & 1) ? dist2[jp >> 1].y : dist2[jp >> 1].x;
          if (dv == lm) jbest = jp;  // min j achieving lm
        }
        unsigned e_best = ((unsigned)t << 4) | (unsigned)jbest;
        wslot[it & 1][wave] =
            (((ull)__float_as_uint(wm)) << 32) | (ull)(8191u - e_best);
      }
      // RAW barrier: drain LDS only; idx publish stores stay in flight.
      asm volatile("s_waitcnt lgkmcnt(0)\n\ts_barrier" ::: "memory");
      {
        const ull* ws = wslot[it & 1];
        ull k0 = ws[0], k1 = ws[1], k2 = ws[2], k3 = ws[3];
        ull k4 = ws[4], k5 = ws[5], k6 = ws[6], k7 = ws[7];
        ull a0 = k0 > k1 ? k0 : k1, a1 = k2 > k3 ? k2 : k3;
        ull a2 = k4 > k5 ? k4 : k5, a3 = k6 > k7 ? k6 : k7;
        ull b0 = a0 > a1 ? a0 : a1, b1 = a2 > a3 ? a2 : a3;
        ull kb = b0 > b1 ? b0 : b1;
        unsigned e = 8191u - (unsigned)(kb & 0xffffffffu);
        if (t == 0) {
          __hip_atomic_store(&idx_out[it + 1], (int)e, __ATOMIC_RELAXED,
                             __HIP_MEMORY_SCOPE_AGENT);
          if ((it & 7) == 7)  // batched ordered publication (1 per 8 iters)
            __hip_atomic_store(&prg[0], it + 2, __ATOMIC_RELEASE,
                               __HIP_MEMORY_SCOPE_AGENT);
        }
        wx = ldsP[e * 3 + 0]; wy = ldsP[e * 3 + 1]; wz = ldsP[e * 3 + 2];
      }
    }
    if (t == 0)  // final publication: all DS entries valid
      __hip_atomic_store(&prg[0], DS, __ATOMIC_RELEASE, __HIP_MEMORY_SCOPE_AGENT);
  } else {
    // ================= worker: static staggered items ======================
    int* hb0 = (int*)smem;                         // [2][2048] = 16 KB
    int* hb1 = (int*)(smem + 16384);               // [2][2048] = 16 KB
    float* Drows = (float*)(smem + 32768);         // [33][64] = 8448 B
    int* nbr = (int*)(smem + 41216);               // [32]
    int* eq = (int*)(smem + 41344);                // [256]
    const int lane = t & 63, wave = t >> 6;
    const int w0 = blk - NFPS;  // 0..239
    for (int item = w0; item < NITEMS; item += NWORK) {
      if (item < NCOSI) {
        // ---- cos chunk: rows item*1024 .. +1023, 2 rows/thread ------------
        float cv = 0.0f;
#pragma unroll
        for (int rr = 0; rr < 2; ++rr) {
          int row = item * 1024 + rr * 512 + t;
          const float4* A = (const float4*)(logits + (size_t)row * CF);
          const float4* Bv = (const float4*)(logits1 + (size_t)row * CF);
          float ab = 0.f, aa = 0.f, bb = 0.f;
#pragma unroll
          for (int i = 0; i < 16; ++i) {
            float4 a = A[i], c4 = Bv[i];
            ab += a.x * c4.x + a.y * c4.y + a.z * c4.z + a.w * c4.w;
            aa += a.x * a.x + a.y * a.y + a.z * a.z + a.w * a.w;
            bb += c4.x * c4.x + c4.y * c4.y + c4.z * c4.z + c4.w * c4.w;
          }
          cv += ab / fmaxf(sqrtf(aa) * sqrtf(bb), 1e-8f);
        }
        cv = wave_sum_bcast(cv);
        if (lane == 0) wloss[wave] = cv;
        __syncthreads();
        if (t == 0) {
          float s = 0.f;
#pragma unroll
          for (int w = 0; w < 8; ++w) s += wloss[w];
          atomicAdd(&acc[0], s);
        }
        __syncthreads();
      } else {
        // ---- knn+group for one query --------------------------------------
        const int qi2 = item - NCOSI;
        const int m = qi2 >> 4, pair = qi2 & 15;
        const int g = pair * DS + m;
        const int view = pair >> 3, b = pair & 7;
        const float* p = (view ? p0sec : p0first) + (size_t)b * NPTS * 3;
        // vectorized point load: 16 consecutive points = 12 dwordx4 / thread
        float f48[48];
        {
          const float4* p4 = (const float4*)p;
#pragma unroll
          for (int i = 0; i < 12; ++i) {
            float4 v4 = p4[t * 12 + i];
            f48[i * 4 + 0] = v4.x; f48[i * 4 + 1] = v4.y;
            f48[i * 4 + 2] = v4.z; f48[i * 4 + 3] = v4.w;
          }
        }
        for (int k = t; k < 4096; k += 512) hb0[k] = 0;
        if (t == 0) {
          // poll the per-instance prog line (read-shared; writer touches it
          // only once per 8 iters) instead of the written idx line.
          int pmv;
          while ((pmv = __hip_atomic_load(&progb[pair * PROGSTRIDE],
                                          __ATOMIC_ACQUIRE,
                                          __HIP_MEMORY_SCOPE_AGENT)) < m + 1)
            __builtin_amdgcn_s_sleep(4);
          int ce = __hip_atomic_load(&idxbuf[g], __ATOMIC_RELAXED,
                                     __HIP_MEMORY_SCOPE_AGENT);
          while ((unsigned)ce >= 8192u) {  // safety net (should not trigger)
            __builtin_amdgcn_s_sleep(2);
            ce = __hip_atomic_load(&idxbuf[g], __ATOMIC_RELAXED,
                                   __HIP_MEMORY_SCOPE_AGENT);
          }
          s_center = ce;
        }
        __syncthreads();
        const int ci = s_center;
        const float qx = p[ci * 3], qy = p[ci * 3 + 1], qz = p[ci * 3 + 2];
        const float qq = qx * qx + qy * qy + qz * qz;
        const int cpy = (t & 1) << 11;  // histogram copy (2 copies)
        unsigned sk[16];  // keys for points e = t*16 + j
#pragma unroll
        for (int j = 0; j < 16; ++j) {
          float sx = f48[j * 3], sy = f48[j * 3 + 1], sz = f48[j * 3 + 2];
          float ss = sx * sx + sy * sy + sz * sz;
          float dt = qx * sx + qy * sy + qz * sz;
          float d = qq + ss - 2.0f * dt;  // same formula as reference
          unsigned u = __float_as_uint(d);
          u = (u & 0x80000000u) ? ~u : (u | 0x80000000u);  // sortable
          sk[j] = u;
        }
        int rrank = 31;
        // ---- pass A: top 11 bits, 2048 bins -------------------------------
#pragma unroll
        for (int j = 0; j < 16; ++j) atomicAdd(&hb0[cpy + (sk[j] >> 21)], 1);
        __syncthreads();
        unsigned pA, pAB, V;
        {
          int b0 = t << 2;
          int c0 = hb0[b0] + hb0[2048 + b0];
          int c1 = hb0[b0 + 1] + hb0[2048 + b0 + 1];
          int c2 = hb0[b0 + 2] + hb0[2048 + b0 + 2];
          int c3 = hb0[b0 + 3] + hb0[2048 + b0 + 3];
          int s = c0 + c1 + c2 + c3;
          int inc = s;
#pragma unroll
          for (int o = 1; o < 64; o <<= 1) {
            int v = __shfl_up(inc, o, 64);
            if (lane >= o) inc += v;
          }
          if (lane == 63) wtot[wave] = inc;
          for (int k = t; k < 4096; k += 512) hb1[k] = 0;  // zero B during scan
          __syncthreads();
          int off = 0;
#pragma unroll
          for (int w = 0; w < 8; ++w) off += (w < wave) ? wtot[w] : 0;
          int exc = off + inc - s;
          if (rrank >= exc && rrank < exc + s) {
            int r2 = rrank - exc; int bin, less;
            if (r2 < c0) { bin = 0; less = 0; }
            else if (r2 < c0 + c1) { bin = 1; less = c0; }
            else if (r2 < c0 + c1 + c2) { bin = 2; less = c0 + c1; }
            else { bin = 3; less = c0 + c1 + c2; }
            s_bl[0] = b0 + bin; s_bl[1] = exc + less;
          }
          __syncthreads();
          pA = (unsigned)s_bl[0];
          rrank -= s_bl[1];
        }
        // ---- pass B: bits [20:10], 2048 bins ------------------------------
#pragma unroll
        for (int j = 0; j < 16; ++j) {
          unsigned u = sk[j];
          if ((u >> 21) == pA) atomicAdd(&hb1[cpy + ((u >> 10) & 2047)], 1);
        }
        __syncthreads();
        {
          int b0 = t << 2;
          int c0 = hb1[b0] + hb1[2048 + b0];
          int c1 = hb1[b0 + 1] + hb1[2048 + b0 + 1];
          int c2 = hb1[b0 + 2] + hb1[2048 + b0 + 2];
          int c3 = hb1[b0 + 3] + hb1[2048 + b0 + 3];
          int s = c0 + c1 + c2 + c3;
          int inc = s;
#pragma unroll
          for (int o = 1; o < 64; o <<= 1) {
            int v = __shfl_up(inc, o, 64);
            if (lane >= o) inc += v;
          }
          if (lane == 63) wtot[wave] = inc;
          for (int k = t; k < 4096; k += 512) hb0[k] = 0;  // zero C buf
          __syncthreads();
          int off = 0;
#pragma unroll
          for (int w = 0; w < 8; ++w) off += (w < wave) ? wtot[w] : 0;
          int exc = off + inc - s;
          if (rrank >= exc && rrank < exc + s) {
            int r2 = rrank - exc; int bin, less;
            if (r2 < c0) { bin = 0; less = 0; }
            else if (r2 < c0 + c1) { bin = 1; less = c0; }
            else if (r2 < c0 + c1 + c2) { bin = 2; less = c0 + c1; }
            else { bin = 3; less = c0 + c1 + c2; }
            s_bl[0] = b0 + bin; s_bl[1] = exc + less;
          }
          __syncthreads();
          pAB = (pA << 11) | (unsigned)s_bl[0];
          rrank -= s_bl[1];
        }
        // ---- pass C: bits [9:0], 1024 bins --------------------------------
        const int cpyC = (t & 1) << 10;
#pragma unroll
        for (int j = 0; j < 16; ++j) {
          unsigned u = sk[j];
          if ((u >> 10) == pAB) atomicAdd(&hb0[cpyC + (u & 1023)], 1);
        }
        __syncthreads();
        {
          int b0 = t << 1;
          int c0 = hb0[b0] + hb0[1024 + b0];
          int c1 = hb0[b0 + 1] + hb0[1024 + b0 + 1];
          int s = c0 + c1;
          int inc = s;
#pragma unroll
          for (int o = 1; o < 64; o <<= 1) {
            int v = __shfl_up(inc, o, 64);
            if (lane >= o) inc += v;
          }
          if (lane == 63) wtot[wave] = inc;
          __syncthreads();
          int off = 0;
#pragma unroll
          for (int w = 0; w < 8; ++w) off += (w < wave) ? wtot[w] : 0;
          int exc = off + inc - s;
          if (rrank >= exc && rrank < exc + s) {
            int r2 = rrank - exc;
            if (r2 < c0) { s_bl[0] = b0; s_bl[1] = exc; }
            else { s_bl[0] = b0 + 1; s_bl[1] = exc + c0; }
          }
          if (t == 0) { ctr = 0; eqctr = 0; }  // folded init (was own barrier)
          __syncthreads();
          V = (pAB << 10) | (unsigned)s_bl[0];
          rrank -= s_bl[1];
        }
        // ---- output set: keys < V, plus (rrank+1) smallest-index == V -----
#pragma unroll
        for (int j = 0; j < 16; ++j) {
          unsigned u = sk[j];
          if (u < V) {
            int s = atomicAdd(&ctr, 1);
            nbr[s] = t * 16 + j;
          } else if (u == V) {
            int s2 = atomicAdd(&eqctr, 1);
            if (s2 < 256) eq[s2] = t * 16 + j;
          }
        }
        __syncthreads();
        if (t == 0) {
          int need = rrank + 1;
          int E = eqctr; if (E > 256) E = 256;
          int base = KNN - need;
          for (int s = 0; s < need; ++s) {
            int mi = 0;
            for (int i = 1; i < E; ++i)
              if (eq[i] < eq[mi]) mi = i;
            nbr[base + s] = eq[mi];
            eq[mi] = 0x7fffffff;
          }
        }
        __syncthreads();
        // ---- group loss (rows 0..31 = neighbors, row 32 = center) ---------
        const float* f = (view ? logits1 : logits) + (size_t)b * NPTS * CF;
        for (int r = wave; r < 33; r += 8) {
          int e = (r < 32) ? nbr[r] : ci;
          Drows[r * 64 + lane] = f[(size_t)e * CF + lane];
        }
        __syncthreads();
        float avg = 0.0f;
#pragma unroll
        for (int r = 0; r < 33; ++r) avg += Drows[r * 64 + lane];
        avg *= (1.0f / 33.0f);
        float na = wave_sum_bcast(avg * avg);
        const float rsna = sqrtf(na);
        float loss = 0.0f;
        for (int r = wave; r < 33; r += 8) {
          float d = Drows[r * 64 + lane];
          float d0 = wave_sum_bcast(d * avg);
          float n0 = wave_sum_bcast(d * d);
          float den = fmaxf(sqrtf(n0) * rsna, 1e-8f);
          loss += -200.0f * (d0 / den) - 0.5f * log1pf(40.0f * n0);
        }
        if (lane == 0) wloss[wave] = loss;
        __syncthreads();
        if (t == 0) {
          float s = 0.f;
#pragma unroll
          for (int w = 0; w < 8; ++w) s += wloss[w];
          atomicAdd(&acc[1 + b], s * (1.0f / 33.0f));
        }
        __syncthreads();
      }
    }
    // ---- completion + last-block finalize --------------------------------
    __syncthreads();
    if (t == 0) {
      int d = __hip_atomic_fetch_add(done, 1, __ATOMIC_ACQ_REL, __HIP_MEMORY_SCOPE_AGENT);
      if (d == NWORK - 1) {
        float a0 = __hip_atomic_load(&acc[0], __ATOMIC_ACQUIRE, __HIP_MEMORY_SCOPE_AGENT);
        float gsum = 0.0f;
        for (int bb = 0; bb < 8; ++bb) {
          float Sb = __hip_atomic_load(&acc[1 + bb], __ATOMIC_ACQUIRE, __HIP_MEMORY_SCOPE_AGENT);
          gsum = (gsum + Sb) * (1.0f / 512.0f);  // /512 exact (pow2)
        }
        gsum *= 0.125f;  // / b
        out[0] = -a0 / 65536.0f + gsum + gsum;
      }
    }
  }
}

extern "C" void kernel_launch(void* const* d_in, const int* in_sizes, int n_in,
                              void* d_out, int out_size, void* d_ws, size_t ws_size,
                              hipStream_t stream) {
  (void)in_sizes; (void)n_in; (void)out_size; (void)ws_size;
  const float* logits  = (const float*)d_in[0];
  const float* logits1 = (const float*)d_in[1];
  const float* p0first = (const float*)d_in[2];
  const float* p0sec   = (const float*)d_in[3];
  float* out = (float*)d_out;

  float* acc = (float*)d_ws;           // [0]=cosSum, [1..8]=S[b], [13]=done
  int* done  = (int*)d_ws + 13;
  int* idxbuf = (int*)d_ws + 16;       // [2*8*512]; 0xAA poison = "unpublished"
  int* progb  = (int*)d_ws + 8704;     // [16*32]; one 128-B line / instance;
                                       // 0xAA poison is negative => "not ready"

  zero_kernel<<<1, 64, 0, stream>>>(acc);
  fused_kernel<<<NFPS + NWORK, 512, DYNLDS, stream>>>(logits, logits1, p0first, p0sec,
                                                      idxbuf, progb, acc, done, out);
}

// Round 7
// 542.317 us; speedup vs baseline: 2.1254x; 1.0007x over previous
//
#include <hip/hip_runtime.h>
#include <cstdint>

#define NPTS 8192
#define NB 8
#define DS 512
#define CF 64
#define KNN 32
#define NFPS 16
#define NWORK 240
#define NCOSI 64
#define NITEMS (NCOSI + 2 * NB * DS)  // 64 cos chunks + 8192 knn+group items
#define DYNLDS 98304                  // max(fps ldsP 96KB, worker bufs ~42KB)

typedef float v2f __attribute__((ext_vector_type(2)));
typedef unsigned long long ull;

// ---- DPP wave-64 reductions (VALU only) -----------------------------------
__device__ __forceinline__ float wave_max63(float x) {
  int v;
  v = __builtin_amdgcn_update_dpp(0, __float_as_int(x), 0x111, 0xf, 0xf, true); x = fmaxf(x, __int_as_float(v));
  v = __builtin_amdgcn_update_dpp(0, __float_as_int(x), 0x112, 0xf, 0xf, true); x = fmaxf(x, __int_as_float(v));
  v = __builtin_amdgcn_update_dpp(0, __float_as_int(x), 0x114, 0xf, 0xf, true); x = fmaxf(x, __int_as_float(v));
  v = __builtin_amdgcn_update_dpp(0, __float_as_int(x), 0x118, 0xf, 0xf, true); x = fmaxf(x, __int_as_float(v));
  v = __builtin_amdgcn_update_dpp(0, __float_as_int(x), 0x142, 0xf, 0xf, true); x = fmaxf(x, __int_as_float(v));
  v = __builtin_amdgcn_update_dpp(0, __float_as_int(x), 0x143, 0xf, 0xf, true); x = fmaxf(x, __int_as_float(v));
  return x;  // valid in lane 63
}

__device__ __forceinline__ float wave_sum_bcast(float x) {
  int v;
  v = __builtin_amdgcn_update_dpp(0, __float_as_int(x), 0x111, 0xf, 0xf, true); x += __int_as_float(v);
  v = __builtin_amdgcn_update_dpp(0, __float_as_int(x), 0x112, 0xf, 0xf, true); x += __int_as_float(v);
  v = __builtin_amdgcn_update_dpp(0, __float_as_int(x), 0x114, 0xf, 0xf, true); x += __int_as_float(v);
  v = __builtin_amdgcn_update_dpp(0, __float_as_int(x), 0x118, 0xf, 0xf, true); x += __int_as_float(v);
  v = __builtin_amdgcn_update_dpp(0, __float_as_int(x), 0x142, 0xf, 0xf, true); x += __int_as_float(v);
  v = __builtin_amdgcn_update_dpp(0, __float_as_int(x), 0x143, 0xf, 0xf, true); x += __int_as_float(v);
  return __int_as_float(__builtin_amdgcn_readlane(__float_as_int(x), 63));
}

// zero acc[0..8] + done([13]); idxbuf stays 0xAA-poisoned (>=8192 sentinel).
__global__ __launch_bounds__(64) void zero_kernel(float* __restrict__ acc) {
  if (threadIdx.x < 16) acc[threadIdx.x] = 0.0f;
}

// ONE fused kernel, 256 blocks x 512 thr, dynamic LDS 98.3KB => 1 block/CU =>
// all 256 blocks co-resident => producer/consumer spin deadlock-free.
//   blocks 0..15  : FPS — R16: LEAN 4-WAVE variant (deconfounds R2). Revised
//                   model of the 2260cy/iter plateau: ~1000cy issue/SIMD
//                   (2 lockstep waves x ~250 instr x 2cy) + ~1000cy serial
//                   tail. R2's 1-wave/SIMD try regressed, but it also added a
//                   64-bit DPP chain, a 32-case switch + dynamic readlanes.
//                   This round: 4 active waves (1/SIMD, 32 pts/thread) with
//                   the MEASURED-GOOD lean machinery of R12/R13 (f32 DPP max,
//                   ballot+ffs tie-break, LDS coord table, 4-slot tree, raw
//                   barrier). Per-SIMD issue ~700cy; tail unchanged. Waves
//                   4-7 only mirror barriers.
//   blocks 16..255: workers with STATIC staggered assignment (R8 lesson).
__global__ __launch_bounds__(512, 2) void fused_kernel(
    const float* __restrict__ logits, const float* __restrict__ logits1,
    const float* __restrict__ p0first, const float* __restrict__ p0sec,
    int* __restrict__ idxbuf, float* __restrict__ acc,
    int* __restrict__ done, float* __restrict__ out) {
  extern __shared__ char smem[];
  __shared__ __align__(16) ull wslot[2][4];
  __shared__ int wtot[8];
  __shared__ int s_bl[2];
  __shared__ int ctr, eqctr, s_center;
  __shared__ float wloss[8];

  const int blk = blockIdx.x;
  const int t = threadIdx.x;

  if (blk < NFPS) {
    // ================= FPS (4 active waves, 1 raw barrier/iter) ============
    float* ldsP = (float*)smem;  // 96 KB winner-lookup table (linear copy of p)
    const int view = blk >> 3, b = blk & 7;
    const float* p = (view ? p0sec : p0first) + (size_t)b * NPTS * 3;
    int* idx_out = idxbuf + blk * DS;
    const int lane = t & 63, wave = t >> 6;

    if (t < 256) {
      // thread t owns points e = t*32 + j, j = 0..31; v2f group g holds
      // j = 2g (.x) and j = 2g+1 (.y).
      v2f px2[16], py2[16], pz2[16], dist2[16];
      {
        const float4* p4 = (const float4*)p;
        float4* l4 = (float4*)ldsP;
#pragma unroll
        for (int k = 0; k < 8; ++k) {
          float4 v0 = p4[t * 24 + 3 * k + 0];
          float4 v1 = p4[t * 24 + 3 * k + 1];
          float4 v2 = p4[t * 24 + 3 * k + 2];
          l4[t * 24 + 3 * k + 0] = v0;  // ldsP[q] == p[q]
          l4[t * 24 + 3 * k + 1] = v1;
          l4[t * 24 + 3 * k + 2] = v2;
          px2[2 * k]     = (v2f){v0.x, v0.w};
          py2[2 * k]     = (v2f){v0.y, v1.x};
          pz2[2 * k]     = (v2f){v0.z, v1.y};
          px2[2 * k + 1] = (v2f){v1.z, v2.y};
          py2[2 * k + 1] = (v2f){v1.w, v2.z};
          pz2[2 * k + 1] = (v2f){v2.x, v2.w};
          dist2[2 * k] = (v2f){3.4e38f, 3.4e38f};
          dist2[2 * k + 1] = (v2f){3.4e38f, 3.4e38f};
        }
      }
#pragma unroll
      for (int g = 0; g < 16; ++g) {
        asm("" : "+v"(px2[g]), "+v"(py2[g]), "+v"(pz2[g]));  // no remat (R4)
      }
      if (t == 0)
        __hip_atomic_store(&idx_out[0], 0, __ATOMIC_RELAXED, __HIP_MEMORY_SCOPE_AGENT);
      float wx = p[0], wy = p[1], wz = p[2];  // seed = point 0
      __syncthreads();

      for (int it = 0; it < DS - 1; ++it) {
        v2f wx2 = (v2f){wx, wx}, wy2 = (v2f){wy, wy}, wz2 = (v2f){wz, wz};
#pragma unroll
        for (int g = 0; g < 16; ++g) {
          v2f dx = px2[g] - wx2, dy = py2[g] - wy2, dz = pz2[g] - wz2;
          v2f nd = dx * dx + dy * dy + dz * dz;
          dist2[g] = __builtin_elementwise_min(dist2[g], nd);
        }
        // lane max via balanced tree (fmax exactly assoc/commut -> identical)
        v2f m0 = __builtin_elementwise_max(dist2[0], dist2[1]);
        v2f m1 = __builtin_elementwise_max(dist2[2], dist2[3]);
        v2f m2 = __builtin_elementwise_max(dist2[4], dist2[5]);
        v2f m3 = __builtin_elementwise_max(dist2[6], dist2[7]);
        v2f m4 = __builtin_elementwise_max(dist2[8], dist2[9]);
        v2f m5 = __builtin_elementwise_max(dist2[10], dist2[11]);
        v2f m6 = __builtin_elementwise_max(dist2[12], dist2[13]);
        v2f m7 = __builtin_elementwise_max(dist2[14], dist2[15]);
        v2f n0 = __builtin_elementwise_max(m0, m1);
        v2f n1 = __builtin_elementwise_max(m2, m3);
        v2f n2 = __builtin_elementwise_max(m4, m5);
        v2f n3 = __builtin_elementwise_max(m6, m7);
        v2f o0 = __builtin_elementwise_max(n0, n1);
        v2f o1 = __builtin_elementwise_max(n2, n3);
        v2f q = __builtin_elementwise_max(o0, o1);
        float lm = fmaxf(q.x, q.y);
        // wave max + broadcast
        float wmv = wave_max63(lm);
        float wm = __int_as_float(__builtin_amdgcn_readlane(__float_as_int(wmv), 63));
        // wave tie-break: lowest candidate lane == smallest e (contiguous map)
        ull cmask = __ballot(lm == wm);
        int winlane = (int)__ffsll(cmask) - 1;
        if (lane == winlane) {
          int jbest = 0;
#pragma unroll
          for (int jp = 31; jp >= 0; --jp) {
            float dv = (jp & 1) ? dist2[jp >> 1].y : dist2[jp >> 1].x;
            if (dv == lm) jbest = jp;  // min j achieving lm
          }
          unsigned e_best = ((unsigned)t << 5) | (unsigned)jbest;
          wslot[it & 1][wave] =
              (((ull)__float_as_uint(wm)) << 32) | (ull)(8191u - e_best);
        }
        // RAW barrier: drain own LDS ops only; publish stores stay in flight.
        asm volatile("s_waitcnt lgkmcnt(0)\n\ts_barrier" ::: "memory");
        {
          const ull* ws = wslot[it & 1];
          ull k0 = ws[0], k1 = ws[1], k2 = ws[2], k3 = ws[3];
          ull a0 = k0 > k1 ? k0 : k1, a1 = k2 > k3 ? k2 : k3;
          ull kb = a0 > a1 ? a0 : a1;
          unsigned e = 8191u - (unsigned)(kb & 0xffffffffu);
          if (t == 0)
            __hip_atomic_store(&idx_out[it + 1], (int)e, __ATOMIC_RELAXED,
                               __HIP_MEMORY_SCOPE_AGENT);
          wx = ldsP[e * 3 + 0]; wy = ldsP[e * 3 + 1]; wz = ldsP[e * 3 + 2];
        }
      }
    } else {
      // waves 4-7: mirror the active waves' barrier count exactly
      __syncthreads();
      for (int it = 0; it < DS - 1; ++it)
        asm volatile("s_waitcnt lgkmcnt(0)\n\ts_barrier" ::: "memory");
    }
  } else {
    // ================= worker: static staggered items ======================
    int* hb0 = (int*)smem;                         // [2][2048] = 16 KB
    int* hb1 = (int*)(smem + 16384);               // [2][2048] = 16 KB
    float* Drows = (float*)(smem + 32768);         // [33][64] = 8448 B
    int* nbr = (int*)(smem + 41216);               // [32]
    int* eq = (int*)(smem + 41344);                // [256]
    const int lane = t & 63, wave = t >> 6;
    const int w0 = blk - NFPS;  // 0..239
    for (int item = w0; item < NITEMS; item += NWORK) {
      if (item < NCOSI) {
        // ---- cos chunk: rows item*1024 .. +1023, 2 rows/thread ------------
        float cv = 0.0f;
#pragma unroll
        for (int rr = 0; rr < 2; ++rr) {
          int row = item * 1024 + rr * 512 + t;
          const float4* A = (const float4*)(logits + (size_t)row * CF);
          const float4* Bv = (const float4*)(logits1 + (size_t)row * CF);
          float ab = 0.f, aa = 0.f, bb = 0.f;
#pragma unroll
          for (int i = 0; i < 16; ++i) {
            float4 a = A[i], c4 = Bv[i];
            ab += a.x * c4.x + a.y * c4.y + a.z * c4.z + a.w * c4.w;
            aa += a.x * a.x + a.y * a.y + a.z * a.z + a.w * a.w;
            bb += c4.x * c4.x + c4.y * c4.y + c4.z * c4.z + c4.w * c4.w;
          }
          cv += ab / fmaxf(sqrtf(aa) * sqrtf(bb), 1e-8f);
        }
        cv = wave_sum_bcast(cv);
        if (lane == 0) wloss[wave] = cv;
        __syncthreads();
        if (t == 0) {
          float s = 0.f;
#pragma unroll
          for (int w = 0; w < 8; ++w) s += wloss[w];
          atomicAdd(&acc[0], s);
        }
        __syncthreads();
      } else {
        // ---- knn+group for one query --------------------------------------
        const int qi2 = item - NCOSI;
        const int m = qi2 >> 4, pair = qi2 & 15;
        const int g = pair * DS + m;
        const int view = pair >> 3, b = pair & 7;
        const float* p = (view ? p0sec : p0first) + (size_t)b * NPTS * 3;
        // vectorized point load: 16 consecutive points = 12 dwordx4 / thread
        float f48[48];
        {
          const float4* p4 = (const float4*)p;
#pragma unroll
          for (int i = 0; i < 12; ++i) {
            float4 v4 = p4[t * 12 + i];
            f48[i * 4 + 0] = v4.x; f48[i * 4 + 1] = v4.y;
            f48[i * 4 + 2] = v4.z; f48[i * 4 + 3] = v4.w;
          }
        }
        for (int k = t; k < 4096; k += 512) hb0[k] = 0;
        if (t == 0) {
          int ce;
          while ((unsigned)(ce = __hip_atomic_load(&idxbuf[g], __ATOMIC_RELAXED,
                                                   __HIP_MEMORY_SCOPE_AGENT)) >= 8192u)
            __builtin_amdgcn_s_sleep(2);
          s_center = ce;
        }
        __syncthreads();
        const int ci = s_center;
        const float qx = p[ci * 3], qy = p[ci * 3 + 1], qz = p[ci * 3 + 2];
        const float qq = qx * qx + qy * qy + qz * qz;
        const int cpy = (t & 1) << 11;  // histogram copy (2 copies)
        unsigned sk[16];  // keys for points e = t*16 + j
#pragma unroll
        for (int j = 0; j < 16; ++j) {
          float sx = f48[j * 3], sy = f48[j * 3 + 1], sz = f48[j * 3 + 2];
          float ss = sx * sx + sy * sy + sz * sz;
          float dt = qx * sx + qy * sy + qz * sz;
          float d = qq + ss - 2.0f * dt;  // same formula as reference
          unsigned u = __float_as_uint(d);
          u = (u & 0x80000000u) ? ~u : (u | 0x80000000u);  // sortable
          sk[j] = u;
        }
        int rrank = 31;
        // ---- pass A: top 11 bits, 2048 bins -------------------------------
#pragma unroll
        for (int j = 0; j < 16; ++j) atomicAdd(&hb0[cpy + (sk[j] >> 21)], 1);
        __syncthreads();
        unsigned pA, pAB, V;
        {
          int b0 = t << 2;
          int c0 = hb0[b0] + hb0[2048 + b0];
          int c1 = hb0[b0 + 1] + hb0[2048 + b0 + 1];
          int c2 = hb0[b0 + 2] + hb0[2048 + b0 + 2];
          int c3 = hb0[b0 + 3] + hb0[2048 + b0 + 3];
          int s = c0 + c1 + c2 + c3;
          int inc = s;
#pragma unroll
          for (int o = 1; o < 64; o <<= 1) {
            int v = __shfl_up(inc, o, 64);
            if (lane >= o) inc += v;
          }
          if (lane == 63) wtot[wave] = inc;
          for (int k = t; k < 4096; k += 512) hb1[k] = 0;  // zero B during scan
          __syncthreads();
          int off = 0;
#pragma unroll
          for (int w = 0; w < 8; ++w) off += (w < wave) ? wtot[w] : 0;
          int exc = off + inc - s;
          if (rrank >= exc && rrank < exc + s) {
            int r2 = rrank - exc; int bin, less;
            if (r2 < c0) { bin = 0; less = 0; }
            else if (r2 < c0 + c1) { bin = 1; less = c0; }
            else if (r2 < c0 + c1 + c2) { bin = 2; less = c0 + c1; }
            else { bin = 3; less = c0 + c1 + c2; }
            s_bl[0] = b0 + bin; s_bl[1] = exc + less;
          }
          __syncthreads();
          pA = (unsigned)s_bl[0];
          rrank -= s_bl[1];
        }
        // ---- pass B: bits [20:10], 2048 bins ------------------------------
#pragma unroll
        for (int j = 0; j < 16; ++j) {
          unsigned u = sk[j];
          if ((u >> 21) == pA) atomicAdd(&hb1[cpy + ((u >> 10) & 2047)], 1);
        }
        __syncthreads();
        {
          int b0 = t << 2;
          int c0 = hb1[b0] + hb1[2048 + b0];
          int c1 = hb1[b0 + 1] + hb1[2048 + b0 + 1];
          int c2 = hb1[b0 + 2] + hb1[2048 + b0 + 2];
          int c3 = hb1[b0 + 3] + hb1[2048 + b0 + 3];
          int s = c0 + c1 + c2 + c3;
          int inc = s;
#pragma unroll
          for (int o = 1; o < 64; o <<= 1) {
            int v = __shfl_up(inc, o, 64);
            if (lane >= o) inc += v;
          }
          if (lane == 63) wtot[wave] = inc;
          for (int k = t; k < 4096; k += 512) hb0[k] = 0;  // zero C buf
          __syncthreads();
          int off = 0;
#pragma unroll
          for (int w = 0; w < 8; ++w) off += (w < wave) ? wtot[w] : 0;
          int exc = off + inc - s;
          if (rrank >= exc && rrank < exc + s) {
            int r2 = rrank - exc; int bin, less;
            if (r2 < c0) { bin = 0; less = 0; }
            else if (r2 < c0 + c1) { bin = 1; less = c0; }
            else if (r2 < c0 + c1 + c2) { bin = 2; less = c0 + c1; }
            else { bin = 3; less = c0 + c1 + c2; }
            s_bl[0] = b0 + bin; s_bl[1] = exc + less;
          }
          __syncthreads();
          pAB = (pA << 11) | (unsigned)s_bl[0];
          rrank -= s_bl[1];
        }
        // ---- pass C: bits [9:0], 1024 bins --------------------------------
        const int cpyC = (t & 1) << 10;
#pragma unroll
        for (int j = 0; j < 16; ++j) {
          unsigned u = sk[j];
          if ((u >> 10) == pAB) atomicAdd(&hb0[cpyC + (u & 1023)], 1);
        }
        __syncthreads();
        {
          int b0 = t << 1;
          int c0 = hb0[b0] + hb0[1024 + b0];
          int c1 = hb0[b0 + 1] + hb0[1024 + b0 + 1];
          int s = c0 + c1;
          int inc = s;
#pragma unroll
          for (int o = 1; o < 64; o <<= 1) {
            int v = __shfl_up(inc, o, 64);
            if (lane >= o) inc += v;
          }
          if (lane == 63) wtot[wave] = inc;
          __syncthreads();
          int off = 0;
#pragma unroll
          for (int w = 0; w < 8; ++w) off += (w < wave) ? wtot[w] : 0;
          int exc = off + inc - s;
          if (rrank >= exc && rrank < exc + s) {
            int r2 = rrank - exc;
            if (r2 < c0) { s_bl[0] = b0; s_bl[1] = exc; }
            else { s_bl[0] = b0 + 1; s_bl[1] = exc + c0; }
          }
          if (t == 0) { ctr = 0; eqctr = 0; }  // folded init (was own barrier)
          __syncthreads();
          V = (pAB << 10) | (unsigned)s_bl[0];
          rrank -= s_bl[1];
        }
        // ---- output set: keys < V, plus (rrank+1) smallest-index == V -----
#pragma unroll
        for (int j = 0; j < 16; ++j) {
          unsigned u = sk[j];
          if (u < V) {
            int s = atomicAdd(&ctr, 1);
            nbr[s] = t * 16 + j;
          } else if (u == V) {
            int s2 = atomicAdd(&eqctr, 1);
            if (s2 < 256) eq[s2] = t * 16 + j;
          }
        }
        __syncthreads();
        if (t == 0) {
          int need = rrank + 1;
          int E = eqctr; if (E > 256) E = 256;
          int base = KNN - need;
          for (int s = 0; s < need; ++s) {
            int mi = 0;
            for (int i = 1; i < E; ++i)
              if (eq[i] < eq[mi]) mi = i;
            nbr[base + s] = eq[mi];
            eq[mi] = 0x7fffffff;
          }
        }
        __syncthreads();
        // ---- group loss (rows 0..31 = neighbors, row 32 = center) ---------
        const float* f = (view ? logits1 : logits) + (size_t)b * NPTS * CF;
        for (int r = wave; r < 33; r += 8) {
          int e = (r < 32) ? nbr[r] : ci;
          Drows[r * 64 + lane] = f[(size_t)e * CF + lane];
        }
        __syncthreads();
        float avg = 0.0f;
#pragma unroll
        for (int r = 0; r < 33; ++r) avg += Drows[r * 64 + lane];
        avg *= (1.0f / 33.0f);
        float na = wave_sum_bcast(avg * avg);
        const float rsna = sqrtf(na);
        float loss = 0.0f;
        for (int r = wave; r < 33; r += 8) {
          float d = Drows[r * 64 + lane];
          float d0 = wave_sum_bcast(d * avg);
          float n0 = wave_sum_bcast(d * d);
          float den = fmaxf(sqrtf(n0) * rsna, 1e-8f);
          loss += -200.0f * (d0 / den) - 0.5f * log1pf(40.0f * n0);
        }
        if (lane == 0) wloss[wave] = loss;
        __syncthreads();
        if (t == 0) {
          float s = 0.f;
#pragma unroll
          for (int w = 0; w < 8; ++w) s += wloss[w];
          atomicAdd(&acc[1 + b], s * (1.0f / 33.0f));
        }
        __syncthreads();
      }
    }
    // ---- completion + last-block finalize --------------------------------
    __syncthreads();
    if (t == 0) {
      int d = __hip_atomic_fetch_add(done, 1, __ATOMIC_ACQ_REL, __HIP_MEMORY_SCOPE_AGENT);
      if (d == NWORK - 1) {
        float a0 = __hip_atomic_load(&acc[0], __ATOMIC_ACQUIRE, __HIP_MEMORY_SCOPE_AGENT);
        float gsum = 0.0f;
        for (int bb = 0; bb < 8; ++bb) {
          float Sb = __hip_atomic_load(&acc[1 + bb], __ATOMIC_ACQUIRE, __HIP_MEMORY_SCOPE_AGENT);
          gsum = (gsum + Sb) * (1.0f / 512.0f);  // /512 exact (pow2)
        }
        gsum *= 0.125f;  // / b
        out[0] = -a0 / 65536.0f + gsum + gsum;
      }
    }
  }
}

extern "C" void kernel_launch(void* const* d_in, const int* in_sizes, int n_in,
                              void* d_out, int out_size, void* d_ws, size_t ws_size,
                              hipStream_t stream) {
  (void)in_sizes; (void)n_in; (void)out_size; (void)ws_size;
  const float* logits  = (const float*)d_in[0];
  const float* logits1 = (const float*)d_in[1];
  const float* p0first = (const float*)d_in[2];
  const float* p0sec   = (const float*)d_in[3];
  float* out = (float*)d_out;

  float* acc = (float*)d_ws;           // [0]=cosSum, [1..8]=S[b], [13]=done
  int* done  = (int*)d_ws + 13;
  int* idxbuf = (int*)d_ws + 16;       // [2*8*512]; 0xAA poison = "unpublished"

  zero_kernel<<<1, 64, 0, stream>>>(acc);
  fused_kernel<<<NFPS + NWORK, 512, DYNLDS, stream>>>(logits, logits1, p0first, p0sec,
                                                      idxbuf, acc, done, out);
}

// Round 8
// 523.098 us; speedup vs baseline: 2.2034x; 1.0367x over previous
//
#include <hip/hip_runtime.h>
#include <cstdint>

#define NPTS 8192
#define NB 8
#define DS 512
#define CF 64
#define KNN 32
#define NFPS 16
#define NWORK 240
#define NCOSI 64
#define NITEMS (NCOSI + 2 * NB * DS)  // 64 cos chunks + 8192 knn+group items
#define DYNLDS 98304                  // max(fps ldsP 96KB, worker bufs ~42KB)

typedef float v2f __attribute__((ext_vector_type(2)));
typedef unsigned long long ull;

// ---- DPP wave-64 reductions (VALU only) -----------------------------------
__device__ __forceinline__ float wave_max63(float x) {
  int v;
  v = __builtin_amdgcn_update_dpp(0, __float_as_int(x), 0x111, 0xf, 0xf, true); x = fmaxf(x, __int_as_float(v));
  v = __builtin_amdgcn_update_dpp(0, __float_as_int(x), 0x112, 0xf, 0xf, true); x = fmaxf(x, __int_as_float(v));
  v = __builtin_amdgcn_update_dpp(0, __float_as_int(x), 0x114, 0xf, 0xf, true); x = fmaxf(x, __int_as_float(v));
  v = __builtin_amdgcn_update_dpp(0, __float_as_int(x), 0x118, 0xf, 0xf, true); x = fmaxf(x, __int_as_float(v));
  v = __builtin_amdgcn_update_dpp(0, __float_as_int(x), 0x142, 0xf, 0xf, true); x = fmaxf(x, __int_as_float(v));
  v = __builtin_amdgcn_update_dpp(0, __float_as_int(x), 0x143, 0xf, 0xf, true); x = fmaxf(x, __int_as_float(v));
  return x;  // valid in lane 63
}

__device__ __forceinline__ float wave_sum_bcast(float x) {
  int v;
  v = __builtin_amdgcn_update_dpp(0, __float_as_int(x), 0x111, 0xf, 0xf, true); x += __int_as_float(v);
  v = __builtin_amdgcn_update_dpp(0, __float_as_int(x), 0x112, 0xf, 0xf, true); x += __int_as_float(v);
  v = __builtin_amdgcn_update_dpp(0, __float_as_int(x), 0x114, 0xf, 0xf, true); x += __int_as_float(v);
  v = __builtin_amdgcn_update_dpp(0, __float_as_int(x), 0x118, 0xf, 0xf, true); x += __int_as_float(v);
  v = __builtin_amdgcn_update_dpp(0, __float_as_int(x), 0x142, 0xf, 0xf, true); x += __int_as_float(v);
  v = __builtin_amdgcn_update_dpp(0, __float_as_int(x), 0x143, 0xf, 0xf, true); x += __int_as_float(v);
  return __int_as_float(__builtin_amdgcn_readlane(__float_as_int(x), 63));
}

// zero acc[0..8] + done([13]); idxbuf stays 0xAA-poisoned (>=8192 sentinel).
__global__ __launch_bounds__(64) void zero_kernel(float* __restrict__ acc) {
  if (threadIdx.x < 16) acc[threadIdx.x] = 0.0f;
}

// ONE fused kernel, 256 blocks x 512 thr, dynamic LDS 98.3KB => 1 block/CU =>
// all 256 blocks co-resident => producer/consumer spin deadlock-free.
//   blocks 0..15  : FPS — R18: R13 body + LOOP-CARRIED REGISTER PIN. Evidence
//                   (VGPR_Count=68 across R0-R4 — too small to hold the 64
//                   coord VGPRs; R5 without the LDS table doubled time with
//                   2x coord traffic): the compiler REMATERIALIZES px/py/pz
//                   from memory EVERY iteration (legal for const __restrict__
//                   loads) — ~98KB/block/iter of hidden L1/L2 traffic is the
//                   unexplained half of the 920ns/iter. Fix: an empty asm at
//                   the top of each iteration with "+v" on all coord+dist
//                   registers makes them loop-carried through the asm —
//                   un-rematerializable, forced register-resident.
//   blocks 16..255: workers with STATIC staggered assignment (R8 lesson).
__global__ __launch_bounds__(512, 2) void fused_kernel(
    const float* __restrict__ logits, const float* __restrict__ logits1,
    const float* __restrict__ p0first, const float* __restrict__ p0sec,
    int* __restrict__ idxbuf, float* __restrict__ acc,
    int* __restrict__ done, float* __restrict__ out) {
  extern __shared__ char smem[];
  __shared__ __align__(16) ull wslot[2][8];
  __shared__ int wtot[8];
  __shared__ int s_bl[2];
  __shared__ int ctr, eqctr, s_center;
  __shared__ float wloss[8];

  const int blk = blockIdx.x;
  const int t = threadIdx.x;

  if (blk < NFPS) {
    // ================= FPS (8 waves, 1 raw barrier/iter) ===================
    float* ldsP = (float*)smem;  // 96 KB winner-lookup table (linear copy of p)
    const int view = blk >> 3, b = blk & 7;
    const float* p = (view ? p0sec : p0first) + (size_t)b * NPTS * 3;
    int* idx_out = idxbuf + blk * DS;
    const int lane = t & 63, wave = t >> 6;
    // lane-contiguous mapping: thread t owns points e = t*16 + j, j = 0..15;
    // v2f group g holds j = 2g (.x) and j = 2g+1 (.y).
    v2f px2[8], py2[8], pz2[8], dist2[8];
    {
      float f48[48];
      const float4* p4 = (const float4*)p;
      float4* l4 = (float4*)ldsP;
#pragma unroll
      for (int i = 0; i < 12; ++i) {
        float4 v4 = p4[t * 12 + i];
        l4[t * 12 + i] = v4;  // ldsP[q] == p[q]
        f48[i * 4 + 0] = v4.x; f48[i * 4 + 1] = v4.y;
        f48[i * 4 + 2] = v4.z; f48[i * 4 + 3] = v4.w;
      }
#pragma unroll
      for (int g = 0; g < 8; ++g) {
        px2[g] = (v2f){f48[6 * g + 0], f48[6 * g + 3]};
        py2[g] = (v2f){f48[6 * g + 1], f48[6 * g + 4]};
        pz2[g] = (v2f){f48[6 * g + 2], f48[6 * g + 5]};
        dist2[g] = (v2f){3.4e38f, 3.4e38f};
      }
    }
    if (t == 0)
      __hip_atomic_store(&idx_out[0], 0, __ATOMIC_RELAXED, __HIP_MEMORY_SCOPE_AGENT);
    float wx = p[0], wy = p[1], wz = p[2];  // seed = point 0
    __syncthreads();  // once; staging drain is fine here

    for (int it = 0; it < DS - 1; ++it) {
      // LOOP-CARRIED PIN: forces coord+dist arrays to stay register-resident.
      // asm output of iter k feeds iter k+1's asm input -> the compiler must
      // treat the values as potentially-modified; remat-from-memory illegal.
#pragma unroll
      for (int g = 0; g < 8; ++g) {
        asm("" : "+v"(px2[g]), "+v"(py2[g]), "+v"(pz2[g]), "+v"(dist2[g]));
      }
      v2f wx2 = (v2f){wx, wx}, wy2 = (v2f){wy, wy}, wz2 = (v2f){wz, wz};
#pragma unroll
      for (int g = 0; g < 8; ++g) {
        v2f dx = px2[g] - wx2, dy = py2[g] - wy2, dz = pz2[g] - wz2;
        v2f nd = dx * dx + dy * dy + dz * dz;
        dist2[g] = __builtin_elementwise_min(dist2[g], nd);
      }
      // lane max via balanced tree (fmax exactly assoc/commut -> identical)
      v2f m0 = __builtin_elementwise_max(dist2[0], dist2[1]);
      v2f m1 = __builtin_elementwise_max(dist2[2], dist2[3]);
      v2f m2 = __builtin_elementwise_max(dist2[4], dist2[5]);
      v2f m3 = __builtin_elementwise_max(dist2[6], dist2[7]);
      v2f n0 = __builtin_elementwise_max(m0, m1);
      v2f n1 = __builtin_elementwise_max(m2, m3);
      v2f q = __builtin_elementwise_max(n0, n1);
      float lm = fmaxf(q.x, q.y);
      // wave max + broadcast
      float wmv = wave_max63(lm);
      float wm = __int_as_float(__builtin_amdgcn_readlane(__float_as_int(wmv), 63));
      // wave tie-break: lowest candidate lane == smallest e (contiguous map)
      ull cmask = __ballot(lm == wm);
      int winlane = (int)__ffsll(cmask) - 1;
      if (lane == winlane) {
        int jbest = 0;
#pragma unroll
        for (int jp = 15; jp >= 0; --jp) {
          float dv = (jp & 1) ? dist2[jp >> 1].y : dist2[jp >> 1].x;
          if (dv == lm) jbest = jp;  // min j achieving lm
        }
        unsigned e_best = ((unsigned)t << 4) | (unsigned)jbest;
        wslot[it & 1][wave] =
            (((ull)__float_as_uint(wm)) << 32) | (ull)(8191u - e_best);
      }
      // RAW barrier: drain LDS only; the idx publish store stays in flight.
      asm volatile("s_waitcnt lgkmcnt(0)\n\ts_barrier" ::: "memory");
      {
        const ull* ws = wslot[it & 1];
        ull k0 = ws[0], k1 = ws[1], k2 = ws[2], k3 = ws[3];
        ull k4 = ws[4], k5 = ws[5], k6 = ws[6], k7 = ws[7];
        ull a0 = k0 > k1 ? k0 : k1, a1 = k2 > k3 ? k2 : k3;
        ull a2 = k4 > k5 ? k4 : k5, a3 = k6 > k7 ? k6 : k7;
        ull b0 = a0 > a1 ? a0 : a1, b1 = a2 > a3 ? a2 : a3;
        ull kb = b0 > b1 ? b0 : b1;
        unsigned e = 8191u - (unsigned)(kb & 0xffffffffu);
        if (t == 0)
          __hip_atomic_store(&idx_out[it + 1], (int)e, __ATOMIC_RELAXED,
                             __HIP_MEMORY_SCOPE_AGENT);
        wx = ldsP[e * 3 + 0]; wy = ldsP[e * 3 + 1]; wz = ldsP[e * 3 + 2];
      }
    }
  } else {
    // ================= worker: static staggered items ======================
    int* hb0 = (int*)smem;                         // [2][2048] = 16 KB
    int* hb1 = (int*)(smem + 16384);               // [2][2048] = 16 KB
    float* Drows = (float*)(smem + 32768);         // [33][64] = 8448 B
    int* nbr = (int*)(smem + 41216);               // [32]
    int* eq = (int*)(smem + 41344);                // [256]
    const int lane = t & 63, wave = t >> 6;
    const int w0 = blk - NFPS;  // 0..239
    for (int item = w0; item < NITEMS; item += NWORK) {
      if (item < NCOSI) {
        // ---- cos chunk: rows item*1024 .. +1023, 2 rows/thread ------------
        float cv = 0.0f;
#pragma unroll
        for (int rr = 0; rr < 2; ++rr) {
          int row = item * 1024 + rr * 512 + t;
          const float4* A = (const float4*)(logits + (size_t)row * CF);
          const float4* Bv = (const float4*)(logits1 + (size_t)row * CF);
          float ab = 0.f, aa = 0.f, bb = 0.f;
#pragma unroll
          for (int i = 0; i < 16; ++i) {
            float4 a = A[i], c4 = Bv[i];
            ab += a.x * c4.x + a.y * c4.y + a.z * c4.z + a.w * c4.w;
            aa += a.x * a.x + a.y * a.y + a.z * a.z + a.w * a.w;
            bb += c4.x * c4.x + c4.y * c4.y + c4.z * c4.z + c4.w * c4.w;
          }
          cv += ab / fmaxf(sqrtf(aa) * sqrtf(bb), 1e-8f);
        }
        cv = wave_sum_bcast(cv);
        if (lane == 0) wloss[wave] = cv;
        __syncthreads();
        if (t == 0) {
          float s = 0.f;
#pragma unroll
          for (int w = 0; w < 8; ++w) s += wloss[w];
          atomicAdd(&acc[0], s);
        }
        __syncthreads();
      } else {
        // ---- knn+group for one query --------------------------------------
        const int qi2 = item - NCOSI;
        const int m = qi2 >> 4, pair = qi2 & 15;
        const int g = pair * DS + m;
        const int view = pair >> 3, b = pair & 7;
        const float* p = (view ? p0sec : p0first) + (size_t)b * NPTS * 3;
        // vectorized point load: 16 consecutive points = 12 dwordx4 / thread
        float f48[48];
        {
          const float4* p4 = (const float4*)p;
#pragma unroll
          for (int i = 0; i < 12; ++i) {
            float4 v4 = p4[t * 12 + i];
            f48[i * 4 + 0] = v4.x; f48[i * 4 + 1] = v4.y;
            f48[i * 4 + 2] = v4.z; f48[i * 4 + 3] = v4.w;
          }
        }
        for (int k = t; k < 4096; k += 512) hb0[k] = 0;
        if (t == 0) {
          int ce;
          while ((unsigned)(ce = __hip_atomic_load(&idxbuf[g], __ATOMIC_RELAXED,
                                                   __HIP_MEMORY_SCOPE_AGENT)) >= 8192u)
            __builtin_amdgcn_s_sleep(2);
          s_center = ce;
        }
        __syncthreads();
        const int ci = s_center;
        const float qx = p[ci * 3], qy = p[ci * 3 + 1], qz = p[ci * 3 + 2];
        const float qq = qx * qx + qy * qy + qz * qz;
        const int cpy = (t & 1) << 11;  // histogram copy (2 copies)
        unsigned sk[16];  // keys for points e = t*16 + j
#pragma unroll
        for (int j = 0; j < 16; ++j) {
          float sx = f48[j * 3], sy = f48[j * 3 + 1], sz = f48[j * 3 + 2];
          float ss = sx * sx + sy * sy + sz * sz;
          float dt = qx * sx + qy * sy + qz * sz;
          float d = qq + ss - 2.0f * dt;  // same formula as reference
          unsigned u = __float_as_uint(d);
          u = (u & 0x80000000u) ? ~u : (u | 0x80000000u);  // sortable
          sk[j] = u;
        }
        int rrank = 31;
        // ---- pass A: top 11 bits, 2048 bins -------------------------------
#pragma unroll
        for (int j = 0; j < 16; ++j) atomicAdd(&hb0[cpy + (sk[j] >> 21)], 1);
        __syncthreads();
        unsigned pA, pAB, V;
        {
          int b0 = t << 2;
          int c0 = hb0[b0] + hb0[2048 + b0];
          int c1 = hb0[b0 + 1] + hb0[2048 + b0 + 1];
          int c2 = hb0[b0 + 2] + hb0[2048 + b0 + 2];
          int c3 = hb0[b0 + 3] + hb0[2048 + b0 + 3];
          int s = c0 + c1 + c2 + c3;
          int inc = s;
#pragma unroll
          for (int o = 1; o < 64; o <<= 1) {
            int v = __shfl_up(inc, o, 64);
            if (lane >= o) inc += v;
          }
          if (lane == 63) wtot[wave] = inc;
          for (int k = t; k < 4096; k += 512) hb1[k] = 0;  // zero B during scan
          __syncthreads();
          int off = 0;
#pragma unroll
          for (int w = 0; w < 8; ++w) off += (w < wave) ? wtot[w] : 0;
          int exc = off + inc - s;
          if (rrank >= exc && rrank < exc + s) {
            int r2 = rrank - exc; int bin, less;
            if (r2 < c0) { bin = 0; less = 0; }
            else if (r2 < c0 + c1) { bin = 1; less = c0; }
            else if (r2 < c0 + c1 + c2) { bin = 2; less = c0 + c1; }
            else { bin = 3; less = c0 + c1 + c2; }
            s_bl[0] = b0 + bin; s_bl[1] = exc + less;
          }
          __syncthreads();
          pA = (unsigned)s_bl[0];
          rrank -= s_bl[1];
        }
        // ---- pass B: bits [20:10], 2048 bins ------------------------------
#pragma unroll
        for (int j = 0; j < 16; ++j) {
          unsigned u = sk[j];
          if ((u >> 21) == pA) atomicAdd(&hb1[cpy + ((u >> 10) & 2047)], 1);
        }
        __syncthreads();
        {
          int b0 = t << 2;
          int c0 = hb1[b0] + hb1[2048 + b0];
          int c1 = hb1[b0 + 1] + hb1[2048 + b0 + 1];
          int c2 = hb1[b0 + 2] + hb1[2048 + b0 + 2];
          int c3 = hb1[b0 + 3] + hb1[2048 + b0 + 3];
          int s = c0 + c1 + c2 + c3;
          int inc = s;
#pragma unroll
          for (int o = 1; o < 64; o <<= 1) {
            int v = __shfl_up(inc, o, 64);
            if (lane >= o) inc += v;
          }
          if (lane == 63) wtot[wave] = inc;
          for (int k = t; k < 4096; k += 512) hb0[k] = 0;  // zero C buf
          __syncthreads();
          int off = 0;
#pragma unroll
          for (int w = 0; w < 8; ++w) off += (w < wave) ? wtot[w] : 0;
          int exc = off + inc - s;
          if (rrank >= exc && rrank < exc + s) {
            int r2 = rrank - exc; int bin, less;
            if (r2 < c0) { bin = 0; less = 0; }
            else if (r2 < c0 + c1) { bin = 1; less = c0; }
            else if (r2 < c0 + c1 + c2) { bin = 2; less = c0 + c1; }
            else { bin = 3; less = c0 + c1 + c2; }
            s_bl[0] = b0 + bin; s_bl[1] = exc + less;
          }
          __syncthreads();
          pAB = (pA << 11) | (unsigned)s_bl[0];
          rrank -= s_bl[1];
        }
        // ---- pass C: bits [9:0], 1024 bins --------------------------------
        const int cpyC = (t & 1) << 10;
#pragma unroll
        for (int j = 0; j < 16; ++j) {
          unsigned u = sk[j];
          if ((u >> 10) == pAB) atomicAdd(&hb0[cpyC + (u & 1023)], 1);
        }
        __syncthreads();
        {
          int b0 = t << 1;
          int c0 = hb0[b0] + hb0[1024 + b0];
          int c1 = hb0[b0 + 1] + hb0[1024 + b0 + 1];
          int s = c0 + c1;
          int inc = s;
#pragma unroll
          for (int o = 1; o < 64; o <<= 1) {
            int v = __shfl_up(inc, o, 64);
            if (lane >= o) inc += v;
          }
          if (lane == 63) wtot[wave] = inc;
          __syncthreads();
          int off = 0;
#pragma unroll
          for (int w = 0; w < 8; ++w) off += (w < wave) ? wtot[w] : 0;
          int exc = off + inc - s;
          if (rrank >= exc && rrank < exc + s) {
            int r2 = rrank - exc;
            if (r2 < c0) { s_bl[0] = b0; s_bl[1] = exc; }
            else { s_bl[0] = b0 + 1; s_bl[1] = exc + c0; }
          }
          if (t == 0) { ctr = 0; eqctr = 0; }  // folded init (was own barrier)
          __syncthreads();
          V = (pAB << 10) | (unsigned)s_bl[0];
          rrank -= s_bl[1];
        }
        // ---- output set: keys < V, plus (rrank+1) smallest-index == V -----
#pragma unroll
        for (int j = 0; j < 16; ++j) {
          unsigned u = sk[j];
          if (u < V) {
            int s = atomicAdd(&ctr, 1);
            nbr[s] = t * 16 + j;
          } else if (u == V) {
            int s2 = atomicAdd(&eqctr, 1);
            if (s2 < 256) eq[s2] = t * 16 + j;
          }
        }
        __syncthreads();
        if (t == 0) {
          int need = rrank + 1;
          int E = eqctr; if (E > 256) E = 256;
          int base = KNN - need;
          for (int s = 0; s < need; ++s) {
            int mi = 0;
            for (int i = 1; i < E; ++i)
              if (eq[i] < eq[mi]) mi = i;
            nbr[base + s] = eq[mi];
            eq[mi] = 0x7fffffff;
          }
        }
        __syncthreads();
        // ---- group loss (rows 0..31 = neighbors, row 32 = center) ---------
        const float* f = (view ? logits1 : logits) + (size_t)b * NPTS * CF;
        for (int r = wave; r < 33; r += 8) {
          int e = (r < 32) ? nbr[r] : ci;
          Drows[r * 64 + lane] = f[(size_t)e * CF + lane];
        }
        __syncthreads();
        float avg = 0.0f;
#pragma unroll
        for (int r = 0; r < 33; ++r) avg += Drows[r * 64 + lane];
        avg *= (1.0f / 33.0f);
        float na = wave_sum_bcast(avg * avg);
        const float rsna = sqrtf(na);
        float loss = 0.0f;
        for (int r = wave; r < 33; r += 8) {
          float d = Drows[r * 64 + lane];
          float d0 = wave_sum_bcast(d * avg);
          float n0 = wave_sum_bcast(d * d);
          float den = fmaxf(sqrtf(n0) * rsna, 1e-8f);
          loss += -200.0f * (d0 / den) - 0.5f * log1pf(40.0f * n0);
        }
        if (lane == 0) wloss[wave] = loss;
        __syncthreads();
        if (t == 0) {
          float s = 0.f;
#pragma unroll
          for (int w = 0; w < 8; ++w) s += wloss[w];
          atomicAdd(&acc[1 + b], s * (1.0f / 33.0f));
        }
        __syncthreads();
      }
    }
    // ---- completion + last-block finalize --------------------------------
    __syncthreads();
    if (t == 0) {
      int d = __hip_atomic_fetch_add(done, 1, __ATOMIC_ACQ_REL, __HIP_MEMORY_SCOPE_AGENT);
      if (d == NWORK - 1) {
        float a0 = __hip_atomic_load(&acc[0], __ATOMIC_ACQUIRE, __HIP_MEMORY_SCOPE_AGENT);
        float gsum = 0.0f;
        for (int bb = 0; bb < 8; ++bb) {
          float Sb = __hip_atomic_load(&acc[1 + bb], __ATOMIC_ACQUIRE, __HIP_MEMORY_SCOPE_AGENT);
          gsum = (gsum + Sb) * (1.0f / 512.0f);  // /512 exact (pow2)
        }
        gsum *= 0.125f;  // / b
        out[0] = -a0 / 65536.0f + gsum + gsum;
      }
    }
  }
}

extern "C" void kernel_launch(void* const* d_in, const int* in_sizes, int n_in,
                              void* d_out, int out_size, void* d_ws, size_t ws_size,
                              hipStream_t stream) {
  (void)in_sizes; (void)n_in; (void)out_size; (void)ws_size;
  const float* logits  = (const float*)d_in[0];
  const float* logits1 = (const float*)d_in[1];
  const float* p0first = (const float*)d_in[2];
  const float* p0sec   = (const float*)d_in[3];
  float* out = (float*)d_out;

  float* acc = (float*)d_ws;           // [0]=cosSum, [1..8]=S[b], [13]=done
  int* done  = (int*)d_ws + 13;
  int* idxbuf = (int*)d_ws + 16;       // [2*8*512]; 0xAA poison = "unpublished"

  zero_kernel<<<1, 64, 0, stream>>>(acc);
  fused_kernel<<<NFPS + NWORK, 512, DYNLDS, stream>>>(logits, logits1, p0first, p0sec,
                                                      idxbuf, acc, done, out);
}